// Round 1
// 131.392 us; speedup vs baseline: 1.0851x; 1.0851x over previous
//
#include <hip/hip_runtime.h>

// LinearAttention (Performer/FAVOR+): B=8, T=S=8192, F=D=64, M=128 (2M=256 features)
// R7: kv_fused rebuilt BARRIER-FREE in the qkv_fused pattern (the fast kernel).
//   - wave w computes phi(k) for ALL 64 s-rows but only its 64 features
//     (sign half x tile half) -> kft tile is wave-private LDS, GEMM reads only it.
//   - v1t deleted: value B-frags built per-lane from global (L1-resident),
//     [v|1] ones-column is a constant fragment. LDS 48.6 -> 36.9 KB.
//   - omega tables stored FRAG-ORDERED (ohf/olf): per-tile operand loads are
//     coalesced 16B/lane instead of 64-lane x 128B-stride scatter.
//   - zero __syncthreads in kv_fused (per-wave DS ordering is HW-guaranteed).
//
// MFMA 16x16x32 bf16 layouts (measured, learn_hip m89/m91):
//   A-frag: lane holds A[m = lane&15][k = (lane>>4)*8 + j], j=0..7
//   B-frag: lane holds B[k = (lane>>4)*8 + j][n = lane&15]
//   C/D   : lane holds D[row = (lane>>4)*4 + reg][col = lane&15], reg=0..3

constexpr int NB = 8;
constexpr int NT = 8192;
constexpr float EPSF = 1e-9f;
constexpr float SCALE = 0.0625f;  // 1/sqrt(2*128)

typedef short s8v __attribute__((ext_vector_type(8)));
typedef short s4v __attribute__((ext_vector_type(4)));
typedef float f4v __attribute__((ext_vector_type(4)));

__device__ inline f4v mfma16(s8v a, s8v b, f4v c) {
  return __builtin_amdgcn_mfma_f32_16x16x32_bf16(a, b, c, 0, 0, 0);
}

__device__ inline short bf16_rne(float f) {
  unsigned u = __builtin_bit_cast(unsigned, f);
  u += 0x7fffu + ((u >> 16) & 1u);
  return (short)(u >> 16);
}
__device__ inline float bf16_to_f(short h) {
  unsigned u = ((unsigned)(unsigned short)h) << 16;
  return __builtin_bit_cast(float, u);
}

// ---- setup: split omega into bf16 hi/lo (Markidis 3-term split), stored in
// MFMA-FRAG ORDER: ohf[((ft*2 + h)*64 + lane)*8 + jj] = omega_hi[m][f] with
// m = ft*16 + (lane&15), f = h*32 + (lane>>4)*8 + jj. A wave's per-tile operand
// load becomes one coalesced s8v per lane. ----
__global__ void setup_omega(const float* __restrict__ omega,
                            short* __restrict__ ohf, short* __restrict__ olf) {
  int i = blockIdx.x * 256 + threadIdx.x;
  if (i >= 128 * 64) return;
  int jj = i & 7;
  int lane = (i >> 3) & 63;
  int h = (i >> 9) & 1;
  int ft = i >> 10;
  int m = ft * 16 + (lane & 15);
  int f = h * 32 + (lane >> 4) * 8 + jj;
  float wv = omega[m * 64 + f];
  short hh = bf16_rne(wv);
  ohf[i] = hh;
  olf[i] = bf16_rne(wv - bf16_to_f(hh));
}

// ---- shared phi helpers ----
struct PhiRows {
  s8v ah0, al0, ah1, al1;  // x fragments (hi/lo) for ksteps 0,1
  float ssr[4];            // |x_row|^2/2 for rows quad*4+reg (C-row indexed)
  float ss;                // |x_row|^2/2 for this lane's own row (lane&15)
};

__device__ inline void split8(f4v a, f4v b, s8v& h, s8v& l) {
  float v[8] = {a.x, a.y, a.z, a.w, b.x, b.y, b.z, b.w};
#pragma unroll
  for (int j = 0; j < 8; ++j) {
    short hh = bf16_rne(v[j]);
    h[j] = hh;
    l[j] = bf16_rne(v[j] - bf16_to_f(hh));
  }
}

__device__ inline void load_phi_rows(const float* __restrict__ xrow_base, int lane, PhiRows& P) {
  const int r = lane & 15, q = lane >> 4;
  const float* p = xrow_base + r * 64 + q * 8;
  f4v u0 = *(const f4v*)(p);
  f4v u1 = *(const f4v*)(p + 4);
  f4v u2 = *(const f4v*)(p + 32);
  f4v u3 = *(const f4v*)(p + 36);
  float ss = u0.x * u0.x + u0.y * u0.y + u0.z * u0.z + u0.w * u0.w
           + u1.x * u1.x + u1.y * u1.y + u1.z * u1.z + u1.w * u1.w
           + u2.x * u2.x + u2.y * u2.y + u2.z * u2.z + u2.w * u2.w
           + u3.x * u3.x + u3.y * u3.y + u3.z * u3.z + u3.w * u3.w;
  ss += __shfl_xor(ss, 16, 64);
  ss += __shfl_xor(ss, 32, 64);
  ss *= 0.5f;
  P.ss = ss;
#pragma unroll
  for (int reg = 0; reg < 4; ++reg) P.ssr[reg] = __shfl(ss, q * 4 + reg, 64);
  split8(u0, u1, P.ah0, P.al0);
  split8(u2, u3, P.ah1, P.al1);
}

// xw C-tile, A = x rows (C: row = x-row q*4+reg, col = omega-row lane&15).
// ft = omega tile index 0..7; tables are frag-ordered (see setup_omega).
__device__ inline f4v phi_xw_tile(const PhiRows& P, const short* __restrict__ ohf,
                                  const short* __restrict__ olf, int ft, int lane) {
  const int o0 = ft * 1024 + lane * 8;
  s8v bh0 = *(const s8v*)(ohf + o0);
  s8v bh1 = *(const s8v*)(ohf + o0 + 512);
  s8v bl0 = *(const s8v*)(olf + o0);
  s8v bl1 = *(const s8v*)(olf + o0 + 512);
  f4v c = {0.f, 0.f, 0.f, 0.f};
  c = mfma16(P.ah0, bh0, c);
  c = mfma16(P.ah1, bh1, c);
  c = mfma16(P.al0, bh0, c);
  c = mfma16(P.al1, bh1, c);
  c = mfma16(P.ah0, bl0, c);
  c = mfma16(P.ah1, bl1, c);
  return c;
}

// xw C-tile, swapped: A = omega rows (C: row = omega-row q*4+reg, col = x-row lane&15).
// x fragments serve as B unchanged: A-frag and B-frag share the per-lane layout.
__device__ inline f4v phi_xw_tile_T(const PhiRows& P, const short* __restrict__ ohf,
                                    const short* __restrict__ olf, int ft, int lane) {
  const int o0 = ft * 1024 + lane * 8;
  s8v ah0 = *(const s8v*)(ohf + o0);
  s8v ah1 = *(const s8v*)(ohf + o0 + 512);
  s8v al0 = *(const s8v*)(olf + o0);
  s8v al1 = *(const s8v*)(olf + o0 + 512);
  f4v c = {0.f, 0.f, 0.f, 0.f};
  c = mfma16(ah0, P.ah0, c);
  c = mfma16(ah1, P.ah1, c);
  c = mfma16(al0, P.ah0, c);
  c = mfma16(al1, P.ah1, c);
  c = mfma16(ah0, P.al0, c);
  c = mfma16(ah1, P.al1, c);
  return c;
}

constexpr int KF_P = 72;          // kft pitch in shorts (144B rows: 16B-aligned, 2-way banks)
constexpr int QF_P = 264;         // qf pitch (shorts): 256 + 8 pad
constexpr int PART_SZ = 65 * 256; // trimmed partial tile (floats->bf16 shorts)

// ---- Kernel KV: fused phi(k) + kv GEMM, BARRIER-FREE ----
// grid 512 = 8b x 64 s-chunks(128). Wave w owns features [w*64, w*64+64):
//   sign = w>>1 (0: +xw half, 1: -xw half), th = w&1 (omega tiles th*4..th*4+3).
// Each wave computes phi for all 64 s-rows of the chunk into its PRIVATE kft
// quarter, then GEMMs against value B-frags built straight from global (L1).
__global__ __launch_bounds__(256, 2) void kv_fused(
    const float* __restrict__ key, const float* __restrict__ value,
    const short* __restrict__ ohf, const short* __restrict__ olf,
    short* __restrict__ partial, float* __restrict__ kvacc, int use_partial) {
  __shared__ short kft[4 * 64 * KF_P];  // 36864 B, wave-private quarters
  const int tid = threadIdx.x, lane = tid & 63, w = tid >> 6;
  const int b = blockIdx.x >> 6;
  const int s0 = (blockIdx.x & 63) * 128;
  const int q = lane >> 4, r15 = lane & 15;
  const int sign = w >> 1, th = w & 1;
  short* kw = kft + w * 64 * KF_P;

  // constant [v|1] ones-column fragment: B[k][n=64..79] = (n==64) ? 1.0 : 0
  s8v vone;
#pragma unroll
  for (int jj = 0; jj < 8; ++jj) vone[jj] = (r15 == 0) ? (short)0x3F80 : (short)0;

  f4v acc[4][5];
#pragma unroll
  for (int j = 0; j < 4; ++j)
#pragma unroll
    for (int n = 0; n < 5; ++n) acc[j][n] = f4v{0.f, 0.f, 0.f, 0.f};

  for (int sc = 0; sc < 2; ++sc) {
    const int sbase = s0 + sc * 64;
    // phi(k): all 64 s-rows (4 row-groups of 16), this wave's 4 feature tiles
#pragma unroll
    for (int rg = 0; rg < 4; ++rg) {
      PhiRows P;
      load_phi_rows(key + ((size_t)b * NT + sbase + rg * 16) * 64, lane, P);
#pragma unroll
      for (int j = 0; j < 4; ++j) {
        f4v c = phi_xw_tile(P, ohf, olf, th * 4 + j, lane);
        s4v pk;
#pragma unroll
        for (int reg = 0; reg < 4; ++reg) {
          float xw = c[reg];  // x-row (rg*16 + q*4+reg), omega-row (th*4+j)*16+r15
          float arg = sign ? (-xw - P.ssr[reg]) : (xw - P.ssr[reg]);
          pk[reg] = bf16_rne((__expf(arg) + EPSF) * SCALE);
        }
        // kft row = local feat j*16+r15 (global w*64 + j*16 + r15), col = s-local
        *(s4v*)(kw + (j * 16 + r15) * KF_P + rg * 16 + q * 4) = pk;
      }
    }
    // GEMM over this chunk's 64 s; B-frags from global value (L1-resident 16KB)
    const float* vb = value + ((size_t)b * NT + sbase) * 64;
#pragma unroll
    for (int ks = 0; ks < 2; ++ks) {
      s8v bf[5];
#pragma unroll
      for (int n = 0; n < 4; ++n) {
#pragma unroll
        for (int jj = 0; jj < 8; ++jj)
          bf[n][jj] = bf16_rne(vb[(ks * 32 + q * 8 + jj) * 64 + n * 16 + r15]);
      }
      bf[4] = vone;
#pragma unroll
      for (int j = 0; j < 4; ++j) {
        s8v a = *(const s8v*)(kw + (j * 16 + r15) * KF_P + ks * 32 + q * 8);
#pragma unroll
        for (int n = 0; n < 5; ++n) acc[j][n] = mfma16(a, bf[n], acc[j][n]);
      }
    }
  }
  // epilogue: C row = feat m (w*64+j*16+q*4+reg), col = d (n*16+r15); keep d<=64
  if (use_partial) {
    short* pb = partial + (size_t)blockIdx.x * PART_SZ;
#pragma unroll
    for (int j = 0; j < 4; ++j) {
      int m = w * 64 + j * 16 + q * 4;
#pragma unroll
      for (int n = 0; n < 4; ++n) {
        int d = n * 16 + r15;
        s4v pk;
#pragma unroll
        for (int reg = 0; reg < 4; ++reg) pk[reg] = bf16_rne(acc[j][n][reg]);
        *(s4v*)(pb + d * 256 + m) = pk;
      }
      if (r15 == 0) {  // n=4 tile: only d=64 is real
        s4v pk;
#pragma unroll
        for (int reg = 0; reg < 4; ++reg) pk[reg] = bf16_rne(acc[j][4][reg]);
        *(s4v*)(pb + 64 * 256 + m) = pk;
      }
    }
  } else {
    float* pb = kvacc + (size_t)b * PART_SZ;
#pragma unroll
    for (int j = 0; j < 4; ++j) {
      int m = w * 64 + j * 16 + q * 4;
#pragma unroll
      for (int n = 0; n < 4; ++n) {
        int d = n * 16 + r15;
#pragma unroll
        for (int reg = 0; reg < 4; ++reg) atomicAdd(pb + d * 256 + m + reg, acc[j][n][reg]);
      }
      if (r15 == 0)
#pragma unroll
        for (int reg = 0; reg < 4; ++reg) atomicAdd(pb + 64 * 256 + m + reg, acc[j][4][reg]);
    }
  }
}

// ---- Kernel finalize: reduce bf16 partials -> kvfrag (B-fragment order) ----
// kvfrag[b][fid=ks*5+n][lane][j]: lane holds B[k=ks*32+(lane>>4)*8+j][d=n*16+(lane&15)]
// d in [65,80) pad slots are written 0.
__global__ __launch_bounds__(256) void kv_finalize(
    const short* __restrict__ partial, const float* __restrict__ kvacc,
    short* __restrict__ kvfrag, int use_partial) {
  int i = blockIdx.x * 256 + threadIdx.x;  // 163840 outputs: (b, d=0..79, m)
  int b = i / 20480;
  int rem = i - b * 20480;
  int d = rem >> 8;
  int m = rem & 255;
  float s = 0.f;
  if (d < 65) {
    if (use_partial) {
      const short* p = partial + (size_t)(b * 64) * PART_SZ + d * 256 + m;
#pragma unroll 8
      for (int c = 0; c < 64; ++c) s += bf16_to_f(p[(size_t)c * PART_SZ]);
    } else {
      s = kvacc[(size_t)b * PART_SZ + d * 256 + m];
    }
  }
  int ks = m >> 5, qq = (m >> 3) & 3, j = m & 7;
  int n = d >> 4, r = d & 15;
  int lane = qq * 16 + r;
  kvfrag[(((size_t)b * 40 + ks * 5 + n) * 64 + lane) * 8 + j] = bf16_rne(s);
}

// ---- Kernel QKV: fused phi(q) + qkv GEMM + normalize ----
// grid 1024 = 8b x 128 t-chunks(64). qf is wave-private -> no barriers.
__global__ __launch_bounds__(256, 4) void qkv_fused(
    const float* __restrict__ query, const short* __restrict__ ohf,
    const short* __restrict__ olf, const short* __restrict__ kvfrag,
    float* __restrict__ out) {
  __shared__ __align__(16) short qf[64 * QF_P];  // [t][feat] bf16, 33792 B
  const int tid = threadIdx.x, lane = tid & 63, w = tid >> 6;
  const int b = blockIdx.x >> 7;
  const int t0 = (blockIdx.x & 127) * 64;
  const int q = lane >> 4, r15 = lane & 15;

  // phi(q), swapped operands: C row = omega-row, col = t -> packed s4v writes
  {
    PhiRows P;
    load_phi_rows(query + ((size_t)b * NT + t0 + w * 16) * 64, lane, P);
    const int t_loc = w * 16 + r15;
#pragma unroll
    for (int ft = 0; ft < 8; ++ft) {
      f4v c = phi_xw_tile_T(P, ohf, olf, ft, lane);
      s4v pk, nk;
#pragma unroll
      for (int reg = 0; reg < 4; ++reg) {
        float xw = c[reg];  // feature ft*16+q*4+reg for x-row r15 (own ss)
        pk[reg] = bf16_rne((__expf(xw - P.ss) + EPSF) * SCALE);
        nk[reg] = bf16_rne((__expf(-xw - P.ss) + EPSF) * SCALE);
      }
      *(s4v*)(qf + t_loc * QF_P + ft * 16 + q * 4) = pk;
      *(s4v*)(qf + t_loc * QF_P + 128 + ft * 16 + q * 4) = nk;
    }
  }
  // GEMM: wave w's A rows = its own 16 t-rows; B-frags straight from global (L2)
  f4v acc[5];
#pragma unroll
  for (int n = 0; n < 5; ++n) acc[n] = f4v{0.f, 0.f, 0.f, 0.f};
  const short* kvb = kvfrag + (size_t)b * 40 * 512;
#pragma unroll
  for (int ks = 0; ks < 8; ++ks) {
    s8v a = *(const s8v*)(qf + (w * 16 + r15) * QF_P + ks * 32 + q * 8);
#pragma unroll
    for (int n = 0; n < 5; ++n) {
      s8v bf = *(const s8v*)(kvb + ((size_t)(ks * 5 + n)) * 512 + lane * 8);
      acc[n] = mfma16(a, bf, acc[n]);
    }
  }
  // denominator: N-tile 4 col 0 (d=64) holds den for rows q*4+reg
  float den_r[4];
#pragma unroll
  for (int reg = 0; reg < 4; ++reg) den_r[reg] = __shfl(acc[4][reg], lane & 48, 64);
  // normalize + stage into this wave's own qf region (its A-reads are done)
  float* stg = (float*)(qf + w * 16 * QF_P);  // 16x68 f32 = 4352 B < 8448 B region
#pragma unroll
  for (int n = 0; n < 4; ++n)
#pragma unroll
    for (int reg = 0; reg < 4; ++reg) {
      int row = q * 4 + reg;
      int col = n * 16 + r15;
      stg[row * 68 + col] = acc[n][reg] / den_r[reg];
    }
  // coalesced copy out (wave-private)
  float* ob = out + ((size_t)b * NT + t0 + w * 16) * 64;
#pragma unroll
  for (int rr = 0; rr < 4; ++rr) {
    int row = rr * 4 + q;
    int c4 = r15 * 4;
    *(f4v*)(ob + row * 64 + c4) = *(const f4v*)(stg + row * 68 + c4);
  }
}

extern "C" void kernel_launch(void* const* d_in, const int* in_sizes, int n_in,
                              void* d_out, int out_size, void* d_ws, size_t ws_size,
                              hipStream_t stream) {
  const float* query = (const float*)d_in[0];  // [8][8192][64]
  const float* value = (const float*)d_in[1];  // [8][8192][64]
  const float* key   = (const float*)d_in[2];  // [8][8192][64]
  const float* omega = (const float*)d_in[3];  // [128][64]
  float* out = (float*)d_out;

  char* ws = (char*)d_ws;
  short* ohf = (short*)ws;                       // 16384 B (frag-ordered hi)
  short* olf = (short*)(ws + 16384);             // 16384 B (frag-ordered lo)
  short* kvfrag = (short*)(ws + 32768);          // 8*40*512*2 = 327680 B
  short* partial = (short*)(ws + 360448);        // 512*65*256*2 = 17039360 B
  float* kvacc = (float*)(ws + 360448);          // fallback: 8*65*256*4 = 532480 B
  const size_t need_full = 360448 + (size_t)512 * PART_SZ * 2;  // ~17.4 MB
  const int use_partial = (ws_size >= need_full) ? 1 : 0;

  setup_omega<<<32, 256, 0, stream>>>(omega, ohf, olf);
  if (!use_partial) {
    hipMemsetAsync(kvacc, 0, (size_t)8 * PART_SZ * 4, stream);  // atomic targets
  }
  kv_fused<<<512, 256, 0, stream>>>(key, value, ohf, olf, partial, kvacc, use_partial);
  kv_finalize<<<640, 256, 0, stream>>>(partial, kvacc, kvfrag, use_partial);
  qkv_fused<<<1024, 256, 0, stream>>>(query, ohf, olf, kvfrag, out);
}

// Round 2
// 129.202 us; speedup vs baseline: 1.1035x; 1.0170x over previous
//
#include <hip/hip_runtime.h>

// LinearAttention (Performer/FAVOR+): B=8, T=S=8192, F=D=64, M=128 (2M=256 features)
// R8: attack the partial-store epilogue — the ONE structural element never changed
// across R0/R1 and absent from the fast qkv_fused kernel.
//   - partial transposed to [m][d] pitch 72; wave stages its 64x65 C-tile into its
//     private kft LDS quarter (idle after GEMM), then does a PURE LINEAR copy of
//     576 s8v (16B fully-coalesced, 1KB/inst) instead of 2.2M scattered 8B stores.
//   - kv_finalize remapped to (m,d) indexing; atomic fallback uses same layout.
//   - everything else byte-identical to R1 (isolate the variable).
//
// MFMA 16x16x32 bf16 layouts (measured, learn_hip m89/m91):
//   A-frag: lane holds A[m = lane&15][k = (lane>>4)*8 + j], j=0..7
//   B-frag: lane holds B[k = (lane>>4)*8 + j][n = lane&15]
//   C/D   : lane holds D[row = (lane>>4)*4 + reg][col = lane&15], reg=0..3

constexpr int NB = 8;
constexpr int NT = 8192;
constexpr float EPSF = 1e-9f;
constexpr float SCALE = 0.0625f;  // 1/sqrt(2*128)

typedef short s8v __attribute__((ext_vector_type(8)));
typedef short s4v __attribute__((ext_vector_type(4)));
typedef float f4v __attribute__((ext_vector_type(4)));

__device__ inline f4v mfma16(s8v a, s8v b, f4v c) {
  return __builtin_amdgcn_mfma_f32_16x16x32_bf16(a, b, c, 0, 0, 0);
}

__device__ inline short bf16_rne(float f) {
  unsigned u = __builtin_bit_cast(unsigned, f);
  u += 0x7fffu + ((u >> 16) & 1u);
  return (short)(u >> 16);
}
__device__ inline float bf16_to_f(short h) {
  unsigned u = ((unsigned)(unsigned short)h) << 16;
  return __builtin_bit_cast(float, u);
}

// ---- setup: split omega into bf16 hi/lo (Markidis 3-term split), stored in
// MFMA-FRAG ORDER: ohf[((ft*2 + h)*64 + lane)*8 + jj] = omega_hi[m][f] with
// m = ft*16 + (lane&15), f = h*32 + (lane>>4)*8 + jj. ----
__global__ void setup_omega(const float* __restrict__ omega,
                            short* __restrict__ ohf, short* __restrict__ olf) {
  int i = blockIdx.x * 256 + threadIdx.x;
  if (i >= 128 * 64) return;
  int jj = i & 7;
  int lane = (i >> 3) & 63;
  int h = (i >> 9) & 1;
  int ft = i >> 10;
  int m = ft * 16 + (lane & 15);
  int f = h * 32 + (lane >> 4) * 8 + jj;
  float wv = omega[m * 64 + f];
  short hh = bf16_rne(wv);
  ohf[i] = hh;
  olf[i] = bf16_rne(wv - bf16_to_f(hh));
}

// ---- shared phi helpers ----
struct PhiRows {
  s8v ah0, al0, ah1, al1;  // x fragments (hi/lo) for ksteps 0,1
  float ssr[4];            // |x_row|^2/2 for rows quad*4+reg (C-row indexed)
  float ss;                // |x_row|^2/2 for this lane's own row (lane&15)
};

__device__ inline void split8(f4v a, f4v b, s8v& h, s8v& l) {
  float v[8] = {a.x, a.y, a.z, a.w, b.x, b.y, b.z, b.w};
#pragma unroll
  for (int j = 0; j < 8; ++j) {
    short hh = bf16_rne(v[j]);
    h[j] = hh;
    l[j] = bf16_rne(v[j] - bf16_to_f(hh));
  }
}

__device__ inline void load_phi_rows(const float* __restrict__ xrow_base, int lane, PhiRows& P) {
  const int r = lane & 15, q = lane >> 4;
  const float* p = xrow_base + r * 64 + q * 8;
  f4v u0 = *(const f4v*)(p);
  f4v u1 = *(const f4v*)(p + 4);
  f4v u2 = *(const f4v*)(p + 32);
  f4v u3 = *(const f4v*)(p + 36);
  float ss = u0.x * u0.x + u0.y * u0.y + u0.z * u0.z + u0.w * u0.w
           + u1.x * u1.x + u1.y * u1.y + u1.z * u1.z + u1.w * u1.w
           + u2.x * u2.x + u2.y * u2.y + u2.z * u2.z + u2.w * u2.w
           + u3.x * u3.x + u3.y * u3.y + u3.z * u3.z + u3.w * u3.w;
  ss += __shfl_xor(ss, 16, 64);
  ss += __shfl_xor(ss, 32, 64);
  ss *= 0.5f;
  P.ss = ss;
#pragma unroll
  for (int reg = 0; reg < 4; ++reg) P.ssr[reg] = __shfl(ss, q * 4 + reg, 64);
  split8(u0, u1, P.ah0, P.al0);
  split8(u2, u3, P.ah1, P.al1);
}

// xw C-tile, A = x rows (C: row = x-row q*4+reg, col = omega-row lane&15).
__device__ inline f4v phi_xw_tile(const PhiRows& P, const short* __restrict__ ohf,
                                  const short* __restrict__ olf, int ft, int lane) {
  const int o0 = ft * 1024 + lane * 8;
  s8v bh0 = *(const s8v*)(ohf + o0);
  s8v bh1 = *(const s8v*)(ohf + o0 + 512);
  s8v bl0 = *(const s8v*)(olf + o0);
  s8v bl1 = *(const s8v*)(olf + o0 + 512);
  f4v c = {0.f, 0.f, 0.f, 0.f};
  c = mfma16(P.ah0, bh0, c);
  c = mfma16(P.ah1, bh1, c);
  c = mfma16(P.al0, bh0, c);
  c = mfma16(P.al1, bh1, c);
  c = mfma16(P.ah0, bl0, c);
  c = mfma16(P.ah1, bl1, c);
  return c;
}

// xw C-tile, swapped: A = omega rows (C: row = omega-row q*4+reg, col = x-row lane&15).
__device__ inline f4v phi_xw_tile_T(const PhiRows& P, const short* __restrict__ ohf,
                                    const short* __restrict__ olf, int ft, int lane) {
  const int o0 = ft * 1024 + lane * 8;
  s8v ah0 = *(const s8v*)(ohf + o0);
  s8v ah1 = *(const s8v*)(ohf + o0 + 512);
  s8v al0 = *(const s8v*)(olf + o0);
  s8v al1 = *(const s8v*)(olf + o0 + 512);
  f4v c = {0.f, 0.f, 0.f, 0.f};
  c = mfma16(ah0, P.ah0, c);
  c = mfma16(ah1, P.ah1, c);
  c = mfma16(al0, P.ah0, c);
  c = mfma16(al1, P.ah1, c);
  c = mfma16(ah0, P.al0, c);
  c = mfma16(ah1, P.al1, c);
  return c;
}

constexpr int KF_P = 72;            // kft pitch in shorts (also partial row pitch)
constexpr int QF_P = 264;           // qf pitch (shorts): 256 + 8 pad
constexpr int PART_P = 72;          // partial pitch: [m=256][d pitch 72] shorts
constexpr int PART_SZ = 256 * PART_P;  // 18432 shorts per block tile

// ---- Kernel KV: fused phi(k) + kv GEMM, barrier-free, coalesced epilogue ----
// grid 512 = 8b x 64 s-chunks(128). Wave w owns features [w*64, w*64+64):
//   sign = w>>1 (0: +xw half, 1: -xw half), th = w&1 (omega tiles th*4..th*4+3).
__global__ __launch_bounds__(256, 2) void kv_fused(
    const float* __restrict__ key, const float* __restrict__ value,
    const short* __restrict__ ohf, const short* __restrict__ olf,
    short* __restrict__ partial, float* __restrict__ kvacc, int use_partial) {
  __shared__ short kft[4 * 64 * KF_P];  // 36864 B, wave-private quarters
  const int tid = threadIdx.x, lane = tid & 63, w = tid >> 6;
  const int b = blockIdx.x >> 6;
  const int s0 = (blockIdx.x & 63) * 128;
  const int q = lane >> 4, r15 = lane & 15;
  const int sign = w >> 1, th = w & 1;
  short* kw = kft + w * 64 * KF_P;

  // constant [v|1] ones-column fragment: B[k][n=64..79] = (n==64) ? 1.0 : 0
  s8v vone;
#pragma unroll
  for (int jj = 0; jj < 8; ++jj) vone[jj] = (r15 == 0) ? (short)0x3F80 : (short)0;

  f4v acc[4][5];
#pragma unroll
  for (int j = 0; j < 4; ++j)
#pragma unroll
    for (int n = 0; n < 5; ++n) acc[j][n] = f4v{0.f, 0.f, 0.f, 0.f};

  for (int sc = 0; sc < 2; ++sc) {
    const int sbase = s0 + sc * 64;
    // phi(k): all 64 s-rows (4 row-groups of 16), this wave's 4 feature tiles
#pragma unroll
    for (int rg = 0; rg < 4; ++rg) {
      PhiRows P;
      load_phi_rows(key + ((size_t)b * NT + sbase + rg * 16) * 64, lane, P);
#pragma unroll
      for (int j = 0; j < 4; ++j) {
        f4v c = phi_xw_tile(P, ohf, olf, th * 4 + j, lane);
        s4v pk;
#pragma unroll
        for (int reg = 0; reg < 4; ++reg) {
          float xw = c[reg];  // x-row (rg*16 + q*4+reg), omega-row (th*4+j)*16+r15
          float arg = sign ? (-xw - P.ssr[reg]) : (xw - P.ssr[reg]);
          pk[reg] = bf16_rne((__expf(arg) + EPSF) * SCALE);
        }
        *(s4v*)(kw + (j * 16 + r15) * KF_P + rg * 16 + q * 4) = pk;
      }
    }
    // GEMM over this chunk's 64 s; B-frags from global value (L1/L2-resident)
    const float* vb = value + ((size_t)b * NT + sbase) * 64;
#pragma unroll
    for (int ks = 0; ks < 2; ++ks) {
      s8v bf[5];
#pragma unroll
      for (int n = 0; n < 4; ++n) {
#pragma unroll
        for (int jj = 0; jj < 8; ++jj)
          bf[n][jj] = bf16_rne(vb[(ks * 32 + q * 8 + jj) * 64 + n * 16 + r15]);
      }
      bf[4] = vone;
#pragma unroll
      for (int j = 0; j < 4; ++j) {
        s8v a = *(const s8v*)(kw + (j * 16 + r15) * KF_P + ks * 32 + q * 8);
#pragma unroll
        for (int n = 0; n < 5; ++n) acc[j][n] = mfma16(a, bf[n], acc[j][n]);
      }
    }
  }
  // ---- epilogue ----
  // C element (j,n,reg): row m_loc = j*16+q*4+reg (wave-local feat), col d = n*16+r15.
  if (use_partial) {
    // Stage the 64x65 tile into this wave's idle kft quarter [m_loc][d] pitch 72,
    // then linear-copy 64*72 shorts = 576 s8v (16B fully coalesced, 1KB/inst).
#pragma unroll
    for (int j = 0; j < 4; ++j) {
#pragma unroll
      for (int n = 0; n < 4; ++n) {
#pragma unroll
        for (int reg = 0; reg < 4; ++reg)
          kw[(j * 16 + q * 4 + reg) * KF_P + n * 16 + r15] = bf16_rne(acc[j][n][reg]);
      }
      if (r15 == 0) {  // n=4 tile: only d=64 is real
#pragma unroll
        for (int reg = 0; reg < 4; ++reg)
          kw[(j * 16 + q * 4 + reg) * KF_P + 64] = bf16_rne(acc[j][4][reg]);
      }
    }
    // partial[block][m=256][d pitch 72]; wave w owns m in [w*64, w*64+64)
    short* pb = partial + (size_t)blockIdx.x * PART_SZ + w * 64 * PART_P;
#pragma unroll
    for (int i = 0; i < 9; ++i) {
      int e = i * 64 + lane;  // 576 s8v = 64 rows x 9 s8v (pitch 72 = 9*8)
      *(s8v*)(pb + e * 8) = *(const s8v*)(kw + e * 8);
    }
  } else {
    // fallback: f32 atomics into kvacc[b][m][d] pitch 72
    float* pb = kvacc + (size_t)b * PART_SZ;
#pragma unroll
    for (int j = 0; j < 4; ++j) {
      int m = w * 64 + j * 16 + q * 4;
#pragma unroll
      for (int n = 0; n < 4; ++n) {
        int d = n * 16 + r15;
#pragma unroll
        for (int reg = 0; reg < 4; ++reg)
          atomicAdd(pb + (size_t)(m + reg) * PART_P + d, acc[j][n][reg]);
      }
      if (r15 == 0)
#pragma unroll
        for (int reg = 0; reg < 4; ++reg)
          atomicAdd(pb + (size_t)(m + reg) * PART_P + 64, acc[j][4][reg]);
    }
  }
}

// ---- Kernel finalize: reduce bf16 partials -> kvfrag (B-fragment order) ----
// partial layout now [blk][m][d] pitch 72. Thread i -> (b, m, d) with consecutive
// threads walking d (coalesced reads). kvfrag layout unchanged:
// kvfrag[b][fid=ks*5+n][lane][j]: lane holds B[k=ks*32+(lane>>4)*8+j][d=n*16+(lane&15)]
__global__ __launch_bounds__(256) void kv_finalize(
    const short* __restrict__ partial, const float* __restrict__ kvacc,
    short* __restrict__ kvfrag, int use_partial) {
  int i = blockIdx.x * 256 + threadIdx.x;  // 163840 outputs: (b, m=0..255, d=0..79)
  int b = i / 20480;
  int rem = i - b * 20480;
  int m = rem / 80;
  int d = rem - m * 80;
  float s = 0.f;
  if (d < 65) {
    if (use_partial) {
      const short* p = partial + (size_t)(b * 64) * PART_SZ + m * PART_P + d;
#pragma unroll 8
      for (int c = 0; c < 64; ++c) s += bf16_to_f(p[(size_t)c * PART_SZ]);
    } else {
      s = kvacc[(size_t)b * PART_SZ + (size_t)m * PART_P + d];
    }
  }
  int ks = m >> 5, qq = (m >> 3) & 3, j = m & 7;
  int n = d >> 4, r = d & 15;
  int lane = qq * 16 + r;
  if (d < 80)
    kvfrag[(((size_t)b * 40 + ks * 5 + n) * 64 + lane) * 8 + j] = bf16_rne(s);
}

// ---- Kernel QKV: fused phi(q) + qkv GEMM + normalize ----
// grid 1024 = 8b x 128 t-chunks(64). qf is wave-private -> no barriers.
__global__ __launch_bounds__(256, 4) void qkv_fused(
    const float* __restrict__ query, const short* __restrict__ ohf,
    const short* __restrict__ olf, const short* __restrict__ kvfrag,
    float* __restrict__ out) {
  __shared__ __align__(16) short qf[64 * QF_P];  // [t][feat] bf16, 33792 B
  const int tid = threadIdx.x, lane = tid & 63, w = tid >> 6;
  const int b = blockIdx.x >> 7;
  const int t0 = (blockIdx.x & 127) * 64;
  const int q = lane >> 4, r15 = lane & 15;

  // phi(q), swapped operands: C row = omega-row, col = t -> packed s4v writes
  {
    PhiRows P;
    load_phi_rows(query + ((size_t)b * NT + t0 + w * 16) * 64, lane, P);
    const int t_loc = w * 16 + r15;
#pragma unroll
    for (int ft = 0; ft < 8; ++ft) {
      f4v c = phi_xw_tile_T(P, ohf, olf, ft, lane);
      s4v pk, nk;
#pragma unroll
      for (int reg = 0; reg < 4; ++reg) {
        float xw = c[reg];  // feature ft*16+q*4+reg for x-row r15 (own ss)
        pk[reg] = bf16_rne((__expf(xw - P.ss) + EPSF) * SCALE);
        nk[reg] = bf16_rne((__expf(-xw - P.ss) + EPSF) * SCALE);
      }
      *(s4v*)(qf + t_loc * QF_P + ft * 16 + q * 4) = pk;
      *(s4v*)(qf + t_loc * QF_P + 128 + ft * 16 + q * 4) = nk;
    }
  }
  // GEMM: wave w's A rows = its own 16 t-rows; B-frags straight from global (L2)
  f4v acc[5];
#pragma unroll
  for (int n = 0; n < 5; ++n) acc[n] = f4v{0.f, 0.f, 0.f, 0.f};
  const short* kvb = kvfrag + (size_t)b * 40 * 512;
#pragma unroll
  for (int ks = 0; ks < 8; ++ks) {
    s8v a = *(const s8v*)(qf + (w * 16 + r15) * QF_P + ks * 32 + q * 8);
#pragma unroll
    for (int n = 0; n < 5; ++n) {
      s8v bf = *(const s8v*)(kvb + ((size_t)(ks * 5 + n)) * 512 + lane * 8);
      acc[n] = mfma16(a, bf, acc[n]);
    }
  }
  // denominator: N-tile 4 col 0 (d=64) holds den for rows q*4+reg
  float den_r[4];
#pragma unroll
  for (int reg = 0; reg < 4; ++reg) den_r[reg] = __shfl(acc[4][reg], lane & 48, 64);
  // normalize + stage into this wave's own qf region (its A-reads are done)
  float* stg = (float*)(qf + w * 16 * QF_P);  // 16x68 f32 = 4352 B < 8448 B region
#pragma unroll
  for (int n = 0; n < 4; ++n)
#pragma unroll
    for (int reg = 0; reg < 4; ++reg) {
      int row = q * 4 + reg;
      int col = n * 16 + r15;
      stg[row * 68 + col] = acc[n][reg] / den_r[reg];
    }
  // coalesced copy out (wave-private)
  float* ob = out + ((size_t)b * NT + t0 + w * 16) * 64;
#pragma unroll
  for (int rr = 0; rr < 4; ++rr) {
    int row = rr * 4 + q;
    int c4 = r15 * 4;
    *(f4v*)(ob + row * 64 + c4) = *(const f4v*)(stg + row * 68 + c4);
  }
}

extern "C" void kernel_launch(void* const* d_in, const int* in_sizes, int n_in,
                              void* d_out, int out_size, void* d_ws, size_t ws_size,
                              hipStream_t stream) {
  const float* query = (const float*)d_in[0];  // [8][8192][64]
  const float* value = (const float*)d_in[1];  // [8][8192][64]
  const float* key   = (const float*)d_in[2];  // [8][8192][64]
  const float* omega = (const float*)d_in[3];  // [128][64]
  float* out = (float*)d_out;

  char* ws = (char*)d_ws;
  short* ohf = (short*)ws;                       // 16384 B (frag-ordered hi)
  short* olf = (short*)(ws + 16384);             // 16384 B (frag-ordered lo)
  short* kvfrag = (short*)(ws + 32768);          // 8*40*512*2 = 327680 B
  short* partial = (short*)(ws + 360448);        // 512*18432*2 = 18874368 B
  float* kvacc = (float*)(ws + 360448);          // fallback: 8*18432*4 = 589824 B
  const size_t need_full = 360448 + (size_t)512 * PART_SZ * 2;  // ~19.2 MB
  const int use_partial = (ws_size >= need_full) ? 1 : 0;

  setup_omega<<<32, 256, 0, stream>>>(omega, ohf, olf);
  if (!use_partial) {
    hipMemsetAsync(kvacc, 0, (size_t)8 * PART_SZ * 4, stream);  // atomic targets
  }
  kv_fused<<<512, 256, 0, stream>>>(key, value, ohf, olf, partial, kvacc, use_partial);
  kv_finalize<<<640, 256, 0, stream>>>(partial, kvacc, kvfrag, use_partial);
  qkv_fused<<<1024, 256, 0, stream>>>(query, ohf, olf, kvfrag, out);
}